// Round 4
// baseline (1457.425 us; speedup 1.0000x reference)
//
#include <hip/hip_runtime.h>

// Persistent per-matrix Newton-Schulz sqrtm. B=256, D=256, iterN=5.
// Round 9: two changes vs round 8, both aimed at the measured 2.4 TB/s
// HBM ceiling (30% of peak) with exactly-as-modeled traffic volume:
//  (1) k-tiled plane layout: bf16 planes stored as 8 contiguous chunks of
//      [256 rows][32 k] (16 KB). Round-8 staging read 64-B granules at
//      512-B stride (k-slice of a row-major plane) from 256 concurrent
//      block streams -> HBM row-buffer thrash. Now each (array, k-tile)
//      stage is one contiguous 16-KB sequential read. LDS image identical
//      to round 8 -> fragment reads / swizzle / MFMA untouched.
//  (2) counted vmcnt (catalog T4): per-tile sync is s_waitcnt vmcnt(8) +
//      raw s_barrier (each wave stages exactly 8 gload16 per tile; after
//      all waves pass their own vmcnt(8)+barrier the current tile is
//      globally complete, next tile's 8 loads stay in flight). Second
//      barrier after the MFMAs (sched_barrier(0)-pinned, rule #18) makes
//      the double-buffer overwrite WAR-safe. vmcnt(0) only at the 12 step
//      boundaries (orders epilogue stores vs next step's DMA reads).
//
// Storage: fp32 emulated as 2-term bf16 planes (hi+lo), product via 3 MFMA:
//   A@B ~= Ah@Bh + Al@Bh + Ah@Bl
// All iterates are symmetric polynomials in A => C = A@B^T == A@B, so both
// operands are read as [outer][k] rows (no transposition anywhere).
//
// LDS swizzle (rule #21, both-sides): physical 8-short slot s of row r holds
// global slot s ^ ((r>>1)&3); applied on the pre-swizzled GLOBAL source
// (linear global_load_lds dest) and the same XOR on the ds_read side.
// Fragment-read bank pattern: exactly 2-way (free, m136).
//
// Chain (A planes live in d_out, dead before the final fp32 overwrite):
//   Z1 = 1.5I - 0.5A
//   3x:  W = A@Z ; T = 1.5W - 0.5(Z@W) ; Z' = T@Z
//   fin: W = A@Z ; T = 1.5W - 0.5(W@Z) ; out = sqrt(normA)*(T@W)

#define DD 256
#define PLN 65536   // shorts per bf16 plane
#define MATN 65536  // floats per fp32 matrix
#define CHK 8192    // shorts per k-tile chunk: 256 rows x 32 k

typedef short s16x8 __attribute__((ext_vector_type(8)));
typedef short s16x4 __attribute__((ext_vector_type(4)));
typedef float f32x4 __attribute__((ext_vector_type(4)));

__device__ __forceinline__ short bf16rtn(float f) {
    unsigned u = __float_as_uint(f);
    u += 0x7FFFu + ((u >> 16) & 1u);   // round-to-nearest-even
    return (short)(u >> 16);
}
__device__ __forceinline__ float bf16tof(short h) {
    return __uint_as_float(((unsigned)(unsigned short)h) << 16);
}
__device__ __forceinline__ void gload16(const short* g, short* l) {
    __builtin_amdgcn_global_load_lds(
        (const __attribute__((address_space(1))) void*)g,
        (__attribute__((address_space(3))) void*)l, 16, 0, 0);
}

// chunked plane offset for element (row, col): chunk = col>>5
__device__ __forceinline__ int coff(int row, int col) {
    return ((col >> 5) << 13) + (row << 5) + (col & 31);
}

__global__ __launch_bounds__(512, 2) void sqrtm_chain(
    const float* __restrict__ x, float* __restrict__ out,
    short* __restrict__ ws)
{
    // 4 arrays x (2 buffers x 8192 shorts) = 128 KiB
    __shared__ __align__(16) short sAh[16384];
    __shared__ __align__(16) short sAl[16384];
    __shared__ __align__(16) short sBh[16384];
    __shared__ __align__(16) short sBl[16384];
    __shared__ float red[8];
    __shared__ float sSc[2];

    const int lb = blockIdx.x, tid = threadIdx.x;
    const int wave = tid >> 6, lane = tid & 63;
    const int ln = lane & 15, quad = lane >> 4;
    const int wr = wave & 3, wc = wave >> 2;   // wave tile: rows wr*64, cols wc*128
    const int sw = (ln >> 1) & 3;              // read-side swizzle key

    const float* X = x + (size_t)lb * MATN;
    float* O = out + (size_t)lb * MATN;
    short* Xpl = (short*)O;                    // A planes live in out region
    short* S0 = ws + (size_t)lb * (6 * (size_t)PLN);
    short* S1 = S0 + 2 * PLN;
    short* S2 = S0 + 4 * PLN;

    // ---------------- setup: normA, A planes, Z1 planes ----------------
    {
        float s = 0.f;
#pragma unroll
        for (int i = 0; i < 32; ++i) {
            const float4 v = *(const float4*)(X + ((i * 512 + tid) << 2));
            s += v.x + v.y + v.z + v.w;
        }
#pragma unroll
        for (int o = 32; o; o >>= 1) s += __shfl_down(s, o, 64);
        if (lane == 0) red[wave] = s;
        __syncthreads();
        if (tid == 0) {
            float t = 0.f;
#pragma unroll
            for (int i = 0; i < 8; ++i) t += red[i];
            sSc[0] = 1.f / t;
            sSc[1] = sqrtf(t);
        }
        __syncthreads();
    }
    const float invN = sSc[0];
    const float sqrtN = sSc[1];
    {
        short* Xh = Xpl;  short* Xl = Xpl + PLN;
        short* Zh = S0;   short* Zl = S0 + PLN;
#pragma unroll 4
        for (int i = 0; i < 32; ++i) {
            const int e = (i * 512 + tid) << 2;
            const int r = e >> 8, c = e & 255;    // c multiple of 4
            const int off = coff(r, c);           // 8B-aligned
            const float4 v = *(const float4*)(X + e);
            const float a0 = invN * v.x, a1 = invN * v.y,
                        a2 = invN * v.z, a3 = invN * v.w;
            s16x4 xh, xl, zh, zl;
            xh[0] = bf16rtn(a0); xl[0] = bf16rtn(a0 - bf16tof(xh[0]));
            xh[1] = bf16rtn(a1); xl[1] = bf16rtn(a1 - bf16tof(xh[1]));
            xh[2] = bf16rtn(a2); xl[2] = bf16rtn(a2 - bf16tof(xh[2]));
            xh[3] = bf16rtn(a3); xl[3] = bf16rtn(a3 - bf16tof(xh[3]));
            const float z0 = ((r == c + 0) ? 1.5f : 0.f) - 0.5f * a0;
            const float z1 = ((r == c + 1) ? 1.5f : 0.f) - 0.5f * a1;
            const float z2 = ((r == c + 2) ? 1.5f : 0.f) - 0.5f * a2;
            const float z3 = ((r == c + 3) ? 1.5f : 0.f) - 0.5f * a3;
            zh[0] = bf16rtn(z0); zl[0] = bf16rtn(z0 - bf16tof(zh[0]));
            zh[1] = bf16rtn(z1); zl[1] = bf16rtn(z1 - bf16tof(zh[1]));
            zh[2] = bf16rtn(z2); zl[2] = bf16rtn(z2 - bf16tof(zh[2]));
            zh[3] = bf16rtn(z3); zl[3] = bf16rtn(z3 - bf16tof(zh[3]));
            *(s16x4*)(Xh + off) = xh; *(s16x4*)(Xl + off) = xl;
            *(s16x4*)(Zh + off) = zh; *(s16x4*)(Zl + off) = zl;
        }
    }
    __syncthreads();   // setup stores drained; same-CU L1 coherent

    // staging coords (fixed per thread): wave pair (2w,2w+1) -> array w;
    // 128 threads/array; thread covers rows r0+32*rr (rr=0..7) of the chunk.
    const int arr = tid >> 7;
    const int idx = tid & 127;
    const int r0 = idx >> 2;                   // 0..31
    const int slot = idx & 3;                  // 0..3
    const int gs = slot ^ ((r0 >> 1) & 3);     // pre-swizzled source slot
    short* lbase = (arr == 0) ? sAh : (arr == 1) ? sAl : (arr == 2) ? sBh : sBl;
    short* const myl = lbase + (wave & 1) * 512;   // wave-uniform LDS dest
    const int goff = r0 * 32 + gs * 8;         // within-chunk short offset

    // step tables: operand/dest slot ids (0,1,2 = ws slots; 3 = A planes)
    const signed char sa_[12] = {3,0,2, 3,1,2, 3,0,2, 3,0,2};
    const signed char sb_[12] = {0,1,0, 1,0,1, 0,1,0, 1,1,0};
    const signed char sc_[12] = {1,2,1, 0,2,0, 1,2,1, 0,2,0};   // sc_[11] unused
    const signed char ax_[12] = {-1,1,-1, -1,0,-1, -1,1,-1, -1,0,-1};
    short* Sl4[4] = {S0, S1, S2, Xpl};

#pragma unroll 1
    for (int st = 0; st < 12; ++st) {
        const short* Ap = Sl4[(int)sa_[st]];
        const short* Bp = Sl4[(int)sb_[st]];
        const short* gsrc = ((arr < 2) ? Ap : Bp) + (arr & 1) * PLN + goff;

        f32x4 acc[4][8];
#pragma unroll
        for (int i = 0; i < 4; ++i)
#pragma unroll
            for (int j = 0; j < 8; ++j) {
                acc[i][j][0] = 0.f; acc[i][j][1] = 0.f;
                acc[i][j][2] = 0.f; acc[i][j][3] = 0.f;
            }

        // prologue: stage k-tile 0 into buf 0 (8 gload16 per wave)
#pragma unroll
        for (int rr = 0; rr < 8; ++rr)
            gload16(gsrc + 0 * CHK + rr * 1024, myl + rr * 1024);

#pragma unroll
        for (int t = 0; t < 8; ++t) {
            if (t < 7) {   // stage tile t+1 into buf (t+1)&1
                const short* g2 = gsrc + (t + 1) * CHK;
                short* l2 = myl + (((t + 1) & 1) << 13);
#pragma unroll
                for (int rr = 0; rr < 8; ++rr)
                    gload16(g2 + rr * 1024, l2 + rr * 1024);
            }
            // tile t arrival: oldest 8 loads done; tile t+1's 8 stay in flight
            if (t < 7) asm volatile("s_waitcnt vmcnt(8)" ::: "memory");
            else       asm volatile("s_waitcnt vmcnt(0)" ::: "memory");
            __builtin_amdgcn_sched_barrier(0);
            __builtin_amdgcn_s_barrier();       // all waves: tile t in LDS

            const int bo = (t & 1) << 13;
            s16x8 ahf[4], alf[4];
#pragma unroll
            for (int i = 0; i < 4; ++i) {
                const int ro = bo + (wr * 64 + i * 16 + ln) * 32
                             + ((quad ^ sw) << 3);
                ahf[i] = *(const s16x8*)(sAh + ro);
                alf[i] = *(const s16x8*)(sAl + ro);
            }
#pragma unroll
            for (int j = 0; j < 8; ++j) {
                const int co = bo + (wc * 128 + j * 16 + ln) * 32
                             + ((quad ^ sw) << 3);
                const s16x8 bh = *(const s16x8*)(sBh + co);
                const s16x8 bl = *(const s16x8*)(sBl + co);
#pragma unroll
                for (int i = 0; i < 4; ++i) {
                    acc[i][j] = __builtin_amdgcn_mfma_f32_16x16x32_bf16(ahf[i], bh, acc[i][j], 0, 0, 0);
                    acc[i][j] = __builtin_amdgcn_mfma_f32_16x16x32_bf16(alf[i], bh, acc[i][j], 0, 0, 0);
                    acc[i][j] = __builtin_amdgcn_mfma_f32_16x16x32_bf16(ahf[i], bl, acc[i][j], 0, 0, 0);
                }
            }
            // pin reads/MFMAs before the WAR barrier (rule #18)
            __builtin_amdgcn_sched_barrier(0);
            __builtin_amdgcn_s_barrier();       // all waves done reading buf t&1
        }

        // epilogue. C/D layout: col=lane&15, row=quad*4+reg (m89/m91-verified).
        if (st == 11) {
#pragma unroll
            for (int i = 0; i < 4; ++i)
#pragma unroll
                for (int j = 0; j < 8; ++j) {
                    const int col = wc * 128 + j * 16 + ln;
#pragma unroll
                    for (int r = 0; r < 4; ++r) {
                        const int row = wr * 64 + i * 16 + quad * 4 + r;
                        O[row * DD + col] = sqrtN * acc[i][j][r];   // fp32 row-major
                    }
                }
        } else {
            short* Ch = Sl4[(int)sc_[st]];
            short* Cl = Ch + PLN;
            const int axs = ax_[st];
            const short* Wh = (axs >= 0) ? (const short*)Sl4[axs] : nullptr;
            const short* Wl = Wh ? Wh + PLN : nullptr;
            const float alpha = (axs >= 0) ? -0.5f : 1.0f;
#pragma unroll
            for (int i = 0; i < 4; ++i)
#pragma unroll
                for (int j = 0; j < 8; ++j) {
                    const int col = wc * 128 + j * 16 + ln;
#pragma unroll
                    for (int r = 0; r < 4; ++r) {
                        const int row = wr * 64 + i * 16 + quad * 4 + r;
                        const int id2 = coff(row, col);
                        float v = alpha * acc[i][j][r];
                        if (Wh) v = fmaf(1.5f, bf16tof(Wh[id2]) + bf16tof(Wl[id2]), v);
                        const short h = bf16rtn(v);
                        Ch[id2] = h;
                        Cl[id2] = bf16rtn(v - bf16tof(h));
                    }
                }
            __syncthreads();   // vmcnt(0): stores visible before next step's DMA
        }
    }
}

extern "C" void kernel_launch(void* const* d_in, const int* in_sizes, int n_in,
                              void* d_out, int out_size, void* d_ws, size_t ws_size,
                              hipStream_t stream)
{
    const float* x = (const float*)d_in[0];
    float* out = (float*)d_out;
    const int NB = 256;

    // ws: nbuf elems x 3 slots x 2 planes; A planes live in d_out.
    short* base = (short*)d_ws;
    long availsh = (long)(ws_size / 2);
    int nbuf = (int)(availsh / (6L * PLN));
    if (nbuf > NB) nbuf = NB;
    if (nbuf < 1) nbuf = 1;

    for (int c0 = 0; c0 < NB; c0 += nbuf) {
        const int n = (NB - c0 < nbuf) ? (NB - c0) : nbuf;
        sqrtm_chain<<<dim3(n), dim3(512), 0, stream>>>(
            x + (size_t)c0 * MATN, out + (size_t)c0 * MATN, base);
    }
}

// Round 6
// 688.674 us; speedup vs baseline: 2.1163x; 2.1163x over previous
//
#include <hip/hip_runtime.h>

// Sqrtm via the reference's coupled iteration, B=256, D=256, iterN=5.
// Round 11: round-10 resubmit (container-level infra failure, no counters)
// with one audited correctness fix: the FINAL T-step is now launched as
// A=Z, B=W (commutative: W@Z == Z@W for polynomials in A) so the LDS-fold
// -- which always folds the B operand -- folds 1.5*W, not 1.5*Z.
// Round-10 deltas vs the 1159us round-6 baseline, unchanged:
//  (1) XCD-pinned block mapping: all 4 tile-blocks of a matrix on ONE XCD
//      (xcd = bid&7 round-robin, m157/m192-verified). The 2nd read of each
//      A/B half-panel becomes an XCD-L2 hit instead of an HBM miss.
//  (2) T-step aux fold from LDS: 1.5*W term folded into acc during the
//      k-tile that stages W[row][*] as the B operand (W IS the B operand in
//      all four T-steps now). Kills 256 scalar global aux loads/thread.
//
// Storage: fp32 emulated as 2-term bf16 planes (hi+lo), product via 3 MFMA:
//   A@B ~= Ah@Bh + Al@Bh + Ah@Bl
// All iterates are symmetric polynomials in A => C = A@B^T == A@B, so both
// operands are read as [outer][k] rows (no transposition anywhere).
//
// Chain (A planes live in d_out, dead before the final fp32 overwrite):
//   Z1 = 1.5I - 0.5A
//   3x:  W = A@Z ; T = 1.5W - 0.5(Z@W) ; Z' = T@Z
//   fin: W = A@Z ; T = 1.5W - 0.5(Z@W) ; out = sqrt(normA)*(T@W)

#define DD 256
#define PLN 65536   // shorts per bf16 plane
#define MATN 65536  // floats per fp32 matrix

typedef short s16x8 __attribute__((ext_vector_type(8)));
typedef short s16x4 __attribute__((ext_vector_type(4)));
typedef float f32x4 __attribute__((ext_vector_type(4)));

__device__ __forceinline__ short bf16rtn(float f) {
    unsigned u = __float_as_uint(f);
    u += 0x7FFFu + ((u >> 16) & 1u);   // round-to-nearest-even
    return (short)(u >> 16);
}
__device__ __forceinline__ float bf16tof(short h) {
    return __uint_as_float(((unsigned)(unsigned short)h) << 16);
}

// 16B global -> LDS direct (DMA). LDS dest is wave-uniform base + lane*16.
__device__ __forceinline__ void gload16(const short* g, short* l) {
    __builtin_amdgcn_global_load_lds(
        (const __attribute__((address_space(1))) void*)g,
        (__attribute__((address_space(3))) void*)l, 16, 0, 0);
}

// ---- setup: sc[lb]=sqrt(normA); X planes = split(invN*x); Z1 planes ----
__global__ __launch_bounds__(256) void setup_kernel(
    const float* __restrict__ x,
    short* __restrict__ zbase, int zstride,
    short* __restrict__ xbase, int xstride,
    float* __restrict__ sc)
{
    const int lb = blockIdx.x, tid = threadIdx.x;
    const float* X = x + (size_t)lb * MATN;
    short* Zh = zbase + (size_t)lb * zstride;  short* Zl = Zh + PLN;
    short* Xh = xbase + (size_t)lb * xstride;  short* Xl = Xh + PLN;
    __shared__ float red[4];
    __shared__ float sInv;

    float s = 0.f;
    for (int i = 0; i < 64; ++i) {
        const float4 v = *(const float4*)(X + ((i * 256 + tid) << 2));
        s += v.x + v.y + v.z + v.w;
    }
    for (int o = 32; o; o >>= 1) s += __shfl_down(s, o, 64);
    if ((tid & 63) == 0) red[tid >> 6] = s;
    __syncthreads();
    if (tid == 0) {
        const float t = red[0] + red[1] + red[2] + red[3];
        sc[lb] = sqrtf(t);
        sInv = 1.f / t;
    }
    __syncthreads();
    const float invN = sInv;

    for (int i = 0; i < 64; ++i) {
        const int e = (i * 256 + tid) << 2;
        const int r = e >> 8, c = e & 255;
        const float4 v = *(const float4*)(X + e);
        const float a0 = invN * v.x, a1 = invN * v.y,
                    a2 = invN * v.z, a3 = invN * v.w;
        s16x4 xh, xl, zh, zl;
        xh[0] = bf16rtn(a0); xl[0] = bf16rtn(a0 - bf16tof(xh[0]));
        xh[1] = bf16rtn(a1); xl[1] = bf16rtn(a1 - bf16tof(xh[1]));
        xh[2] = bf16rtn(a2); xl[2] = bf16rtn(a2 - bf16tof(xh[2]));
        xh[3] = bf16rtn(a3); xl[3] = bf16rtn(a3 - bf16tof(xh[3]));
        const float z0 = ((r == c + 0) ? 1.5f : 0.f) - 0.5f * a0;
        const float z1 = ((r == c + 1) ? 1.5f : 0.f) - 0.5f * a1;
        const float z2 = ((r == c + 2) ? 1.5f : 0.f) - 0.5f * a2;
        const float z3 = ((r == c + 3) ? 1.5f : 0.f) - 0.5f * a3;
        zh[0] = bf16rtn(z0); zl[0] = bf16rtn(z0 - bf16tof(zh[0]));
        zh[1] = bf16rtn(z1); zl[1] = bf16rtn(z1 - bf16tof(zh[1]));
        zh[2] = bf16rtn(z2); zl[2] = bf16rtn(z2 - bf16tof(zh[2]));
        zh[3] = bf16rtn(z3); zl[3] = bf16rtn(z3 - bf16tof(zh[3]));
        *(s16x4*)(Xh + e) = xh; *(s16x4*)(Xl + e) = xl;
        *(s16x4*)(Zh + e) = zh; *(s16x4*)(Zl + e) = zl;
    }
}

// ---- batched GEMM: C = alpha*(A@B) [+ 1.5*B folded from LDS if fold].
// Both operands read as rows (C = A@B^T, valid by symmetry).
// grid = 4*n blocks; XCD-pinned mapping when swz (n%8==0):
//   xcd = bid&7, s = bid>>3, lb = xcd*(n/8) + s/4, tile = s&3.
__global__ __launch_bounds__(256) void gemm_ns(
    const short* Ahg, int astride,
    const short* Bhg, int bstride,
    short* __restrict__ Chg, int cstride,
    float* __restrict__ Cfg, int cfstride,
    const float* __restrict__ sc,
    float alpha, int fold, int usesc, int nmat, int swz)
{
    __shared__ __align__(16) short sAh[4096];
    __shared__ __align__(16) short sAl[4096];
    __shared__ __align__(16) short sBh[4096];
    __shared__ __align__(16) short sBl[4096];

    const int bid = blockIdx.x;
    int lb, t;
    if (swz) {
        const int xcd = bid & 7, s = bid >> 3;
        lb = xcd * (nmat >> 3) + (s >> 2);
        t = s & 3;
    } else {
        lb = bid >> 2;
        t = bid & 3;
    }
    const int tileR = (t >> 1) << 7, tileC = (t & 1) << 7;
    const int tid = threadIdx.x, lane = tid & 63, wave = tid >> 6;
    const int wr = wave >> 1, wc = wave & 1, ln = lane & 15, quad = lane >> 4;

    const short* Ah = Ahg + (size_t)lb * astride;  const short* Al = Ah + PLN;
    const short* Bh = Bhg + (size_t)lb * bstride;  const short* Bl = Bh + PLN;

    // staging coords: 4 threads (16B each) per row
    const int srow = tid >> 2;                       // 0..63
    const int gs = (tid & 3) ^ ((tid >> 3) & 3);     // swizzled source slot
    const size_t aoff0 = (size_t)(tileR + srow) * DD + gs * 8;
    const size_t aoff1 = aoff0 + (size_t)64 * DD;
    const size_t boff0 = (size_t)(tileC + srow) * DD + gs * 8;
    const size_t boff1 = boff0 + (size_t)64 * DD;
    const int ldo0 = wave * 512;                     // shorts, wave-uniform
    const int ldo1 = 2048 + wave * 512;

    f32x4 acc[4][4];
#pragma unroll
    for (int i = 0; i < 4; ++i)
#pragma unroll
        for (int j = 0; j < 4; ++j) {
            acc[i][j][0] = 0.f; acc[i][j][1] = 0.f;
            acc[i][j][2] = 0.f; acc[i][j][3] = 0.f;
        }

    const int fo = ((quad ^ ((ln >> 1) & 3)) << 3);  // swizzled read slot

    for (int kt = 0; kt < DD; kt += 32) {
        __syncthreads();
        gload16(Ah + aoff0 + kt, sAh + ldo0);
        gload16(Ah + aoff1 + kt, sAh + ldo1);
        gload16(Al + aoff0 + kt, sAl + ldo0);
        gload16(Al + aoff1 + kt, sAl + ldo1);
        gload16(Bh + boff0 + kt, sBh + ldo0);
        gload16(Bh + boff1 + kt, sBh + ldo1);
        gload16(Bl + boff0 + kt, sBl + ldo0);
        gload16(Bl + boff1 + kt, sBl + ldo1);
        __syncthreads();

        s16x8 ahf[4], alf[4];
#pragma unroll
        for (int i = 0; i < 4; ++i) {
            const int ro = (wr * 64 + i * 16 + ln) * 32 + fo;
            ahf[i] = *(const s16x8*)(sAh + ro);
            alf[i] = *(const s16x8*)(sAl + ro);
        }
#pragma unroll
        for (int j = 0; j < 4; ++j) {
            const int co = (wc * 64 + j * 16 + ln) * 32 + fo;
            const s16x8 bh = *(const s16x8*)(sBh + co);
            const s16x8 bl = *(const s16x8*)(sBl + co);
#pragma unroll
            for (int i = 0; i < 4; ++i) {
                acc[i][j] = __builtin_amdgcn_mfma_f32_16x16x32_bf16(ahf[i], bh, acc[i][j], 0, 0, 0);
                acc[i][j] = __builtin_amdgcn_mfma_f32_16x16x32_bf16(alf[i], bh, acc[i][j], 0, 0, 0);
                acc[i][j] = __builtin_amdgcn_mfma_f32_16x16x32_bf16(ahf[i], bl, acc[i][j], 0, 0, 0);
            }
        }

        // fold 1.5*W (aux == B operand) while its granules sit in B-LDS:
        // want W[row][col]; LDS B holds W[tileC+nc][kt+kr]; with nc=col-tileC,
        // kr=row-kt this reads W[col][row] == W[row][col] (W symmetric).
        // alpha=-0.5 in fold steps -> add -3*W so alpha*acc carries +1.5*W.
        if (fold) {
            const int base = kt - tileR - wr * 64;   // wave-uniform
            if (0 <= base && base < 64) {
#pragma unroll
                for (int i = 0; i < 4; ++i) {
                    const int lr = i * 16 - base;     // row offset in k-tile
                    if (0 <= lr && lr < 32) {
#pragma unroll
                        for (int j = 0; j < 4; ++j) {
                            const int nc = wc * 64 + j * 16 + ln;
                            // physical slot of kr: (kr>>3) ^ ((nc>>1)&3)
                            const int key = (nc >> 1) & 3;
#pragma unroll
                            for (int r = 0; r < 4; ++r) {
                                const int kr = lr + quad * 4 + r;
                                const int ph = nc * 32
                                    + (((kr >> 3) ^ key) << 3) + (kr & 7);
                                const float w = bf16tof(sBh[ph])
                                              + bf16tof(sBl[ph]);
                                acc[i][j][r] = fmaf(-3.0f, w, acc[i][j][r]);
                            }
                        }
                    }
                }
            }
        }
    }

    // Epilogue. C/D layout: col=lane&15, row=quad*4+reg (m89/m91-verified).
    const float alphav = usesc ? sc[lb] : alpha;
    if (Chg) {
        short* Ch = Chg + (size_t)lb * cstride;  short* Cl = Ch + PLN;
#pragma unroll
        for (int i = 0; i < 4; ++i)
#pragma unroll
            for (int j = 0; j < 4; ++j) {
                const int col = tileC + wc * 64 + j * 16 + ln;
#pragma unroll
                for (int r = 0; r < 4; ++r) {
                    const int row = tileR + wr * 64 + i * 16 + quad * 4 + r;
                    const int idx = row * DD + col;
                    const float v = alphav * acc[i][j][r];
                    const short h = bf16rtn(v);
                    Ch[idx] = h;
                    Cl[idx] = bf16rtn(v - bf16tof(h));
                }
            }
    } else {
        float* Cf = Cfg + (size_t)lb * cfstride;
#pragma unroll
        for (int i = 0; i < 4; ++i)
#pragma unroll
            for (int j = 0; j < 4; ++j) {
                const int col = tileC + wc * 64 + j * 16 + ln;
#pragma unroll
                for (int r = 0; r < 4; ++r) {
                    const int row = tileR + wr * 64 + i * 16 + quad * 4 + r;
                    Cf[row * DD + col] = alphav * acc[i][j][r];
                }
            }
    }
}

extern "C" void kernel_launch(void* const* d_in, const int* in_sizes, int n_in,
                              void* d_out, int out_size, void* d_ws, size_t ws_size,
                              hipStream_t stream)
{
    const float* x = (const float*)d_in[0];
    float* out = (float*)d_out;
    const int NB = 256;

    // ws layout: [512 floats sc/header][nbuf elems x 6 bf16 planes]
    // X planes live in d_out (dead before the final fp32 overwrite).
    float* sc = (float*)d_ws;
    short* base = (short*)(sc + 512);
    long availsh = (long)(ws_size / 2) - 1024;
    int nbuf = (int)(availsh / (6L * PLN));
    if (nbuf > NB) nbuf = NB;
    if (nbuf < 1) nbuf = 1;
    const int ES = 6 * PLN;   // ws element stride (shorts)
    const int EX = 2 * PLN;   // d_out element stride (shorts)

    for (int c0 = 0; c0 < NB; c0 += nbuf) {
        const int n = (NB - c0 < nbuf) ? (NB - c0) : nbuf;
        const int swz = (n % 8 == 0) ? 1 : 0;
        const float* xs = x + (size_t)c0 * MATN;
        float* os = out + (size_t)c0 * MATN;
        short* XH = (short*)os;
        short* SA = base;
        short* SB = base + 2 * PLN;
        short* TT = base + 4 * PLN;
        const dim3 G(4 * n), T(256);

        setup_kernel<<<n, 256, 0, stream>>>(xs, SA, ES, XH, EX, sc);

#define GEMM_B(AH, AS, BH, BS, CH, AL, FD) \
        gemm_ns<<<G, T, 0, stream>>>((AH), (AS), (BH), (BS), (CH), ES, \
                                     nullptr, 0, sc, (AL), (FD), 0, n, swz)

        // it1 (Z in SA)
        GEMM_B(XH, EX, SA, ES, SB, 1.f, 0);    // W = A@Z -> SB
        GEMM_B(SA, ES, SB, ES, TT, -0.5f, 1);  // T = 1.5W-0.5(Z@W), W folded
        GEMM_B(TT, ES, SA, ES, SB, 1.f, 0);    // Z' = T@Z -> SB
        // it2 (Z in SB)
        GEMM_B(XH, EX, SB, ES, SA, 1.f, 0);
        GEMM_B(SB, ES, SA, ES, TT, -0.5f, 1);
        GEMM_B(TT, ES, SB, ES, SA, 1.f, 0);
        // it3 (Z in SA)
        GEMM_B(XH, EX, SA, ES, SB, 1.f, 0);
        GEMM_B(SA, ES, SB, ES, TT, -0.5f, 1);
        GEMM_B(TT, ES, SA, ES, SB, 1.f, 0);
        // final (Z in SB)
        GEMM_B(XH, EX, SB, ES, SA, 1.f, 0);    // W = Y -> SA
        // final T-step launched as A=Z(SB), B=W(SA) so the fold hits W
        // (W@Z == Z@W: all iterates commute as polynomials in A).
        GEMM_B(SB, ES, SA, ES, TT, -0.5f, 1);  // T = 1.5W-0.5(Z@W), W folded
        gemm_ns<<<G, T, 0, stream>>>(TT, ES, SA, ES, nullptr, 0, os, MATN,
                                     sc, 0.f, 0, 1, n, swz);  // out = sqrtN*(T@W)
#undef GEMM_B
    }
}